// Round 4
// baseline (522.996 us; speedup 1.0000x reference)
//
#include <hip/hip_runtime.h>
#include <hip/hip_bf16.h>
#include <math.h>

// Problem dims (fixed): T=512, B=256, I=128, H=256
#define TT 512
#define BB 256
#define II 128
#define HH 256

typedef float f4 __attribute__((ext_vector_type(4)));

// ---------------------------------------------------------------------------
// Kernel 1: input projection  xi[m][n] = sum_k x[m][k]*Wi[n][k] + bh[n]
//   M = T*B = 131072, K = 128, N = 256. Written into d_out (later overwritten
//   in-place by the recurrence with h_t).
// ---------------------------------------------------------------------------
__global__ __launch_bounds__(256) void proj_kernel(
    const float* __restrict__ x, const float* __restrict__ Wi,
    const float* __restrict__ bh, float* __restrict__ out)
{
    __shared__ float xt[128][68];
    __shared__ float wt[128][64];

    const int tid = threadIdx.x;
    const int m0 = blockIdx.x * 64;
    const int j0 = blockIdx.y * 64;

    {
        const int r  = tid & 63;
        const int kc = tid >> 6;
        const float* xsrc = x  + (size_t)(m0 + r) * II + kc * 32;
        const float* wsrc = Wi + (size_t)(j0 + r) * II + kc * 32;
#pragma unroll
        for (int u = 0; u < 8; ++u) {
            float4 v = *(const float4*)(xsrc + u * 4);
            int k = kc * 32 + u * 4;
            xt[k + 0][r] = v.x; xt[k + 1][r] = v.y;
            xt[k + 2][r] = v.z; xt[k + 3][r] = v.w;
        }
#pragma unroll
        for (int u = 0; u < 8; ++u) {
            float4 v = *(const float4*)(wsrc + u * 4);
            int k = kc * 32 + u * 4;
            wt[k + 0][r] = v.x; wt[k + 1][r] = v.y;
            wt[k + 2][r] = v.z; wt[k + 3][r] = v.w;
        }
    }
    __syncthreads();

    const int ty = tid >> 4, tx = tid & 15;
    const int r0 = ty * 4, c0 = tx * 4;
    float acc[4][4] = {};
#pragma unroll 4
    for (int k = 0; k < 128; ++k) {
        float4 a = *(const float4*)&xt[k][r0];
        float4 b = *(const float4*)&wt[k][c0];
        float av[4] = {a.x, a.y, a.z, a.w};
        float bv[4] = {b.x, b.y, b.z, b.w};
#pragma unroll
        for (int i = 0; i < 4; ++i)
#pragma unroll
            for (int j = 0; j < 4; ++j)
                acc[i][j] += av[i] * bv[j];
    }

    float4 bias = *(const float4*)(bh + j0 + c0);
    float bvv[4] = {bias.x, bias.y, bias.z, bias.w};
#pragma unroll
    for (int i = 0; i < 4; ++i) {
        float4 o;
        o.x = acc[i][0] + bvv[0];
        o.y = acc[i][1] + bvv[1];
        o.z = acc[i][2] + bvv[2];
        o.w = acc[i][3] + bvv[3];
        *(float4*)(out + (size_t)(m0 + r0 + i) * HH + j0 + c0) = o;
    }
}

// ---------------------------------------------------------------------------
// tanh(x) = 1 - 2/(exp(2x)+1). abs err ~1e-6; absmax was unchanged (0.0039)
// when this replaced tanhf in round 2, so it's numerically safe here.
// ---------------------------------------------------------------------------
__device__ __forceinline__ float fast_tanh(float x) {
    float e = __expf(2.0f * x);
    return 1.0f - 2.0f * __builtin_amdgcn_rcpf(e + 1.0f);
}

// Opaque (un-rematerializable) 16B global load: asm results can't be re-sunk
// into the loop. Round-1 plain loads: compiler sank them (VGPR=80).
__device__ __forceinline__ f4 ld_f4_opaque(const float* p) {
    f4 r;
    asm volatile("global_load_dwordx4 %0, %1, off"
                 : "=v"(r) : "v"(p));
    return r;
}

// ---------------------------------------------------------------------------
// Kernel 2: recurrence. One block per batch row. 1024 threads = 16 waves
// (was 8): per-thread Wh fragment is now 4 cols x 16 k = 64 floats (16 f4),
// half the round-3 footprint, so it fits the 128-VGPR cap of
// __launch_bounds__(1024,4) with headroom -> allocator keeps it resident
// (round-3's 128-float fragment was spilled despite opaque loads: VGPR=88).
//   FMA phase: thread (lane, wave q) owns cols lane*4..+4, k in [q*16,q*16+16).
//     h k-slice read = wave-uniform LDS broadcast (free).
//   Reduce: thread tid -> col=tid>>2, r=tid&3; 4 part-rows + 2 shfl_xor;
//     part stride 260 makes the 4-lane same-bank group 2-way (free, m136).
//   h_t global store deferred to step t+1's top, coalesced from LDS by
//     tid<256, so the vmcnt-before-barrier drain hides under the FMA phase.
// ---------------------------------------------------------------------------
__global__ __launch_bounds__(1024, 4) void rec_kernel(
    const float* __restrict__ Wh, const float* __restrict__ h0,
    float* __restrict__ io)
{
    __shared__ float h[HH];
    __shared__ float part[16][HH + 4];   // stride 260 floats (1040B, 16B-aligned)

    const int tid  = threadIdx.x;
    const int b    = blockIdx.x;
    const int lane = tid & 63;
    const int q    = tid >> 6;     // wave id, 0..15
    const int jb   = lane * 4;     // FMA: first of 4 output columns
    const int kb   = q * 16;       // FMA: k-slice base (16 k)

    const int rcol = tid >> 2;     // reduce: column 0..255
    const int rr   = tid & 3;      // reduce: partial quarter 0..3

    // persistent Wh fragment: 4 cols x 16 k = 16 f4 = 64 VGPRs
    f4 w[4][4];
#pragma unroll
    for (int c = 0; c < 4; ++c)
#pragma unroll
        for (int m = 0; m < 4; ++m)
            w[c][m] = ld_f4_opaque(Wh + (size_t)(jb + c) * HH + kb + m * 4);
    asm volatile("s_waitcnt vmcnt(0)" ::: "memory");
    __builtin_amdgcn_sched_barrier(0);   // rule #18: keep uses after waitcnt

    if (tid < HH) h[tid] = h0[(size_t)b * HH + tid];
    __syncthreads();

    const size_t stride = (size_t)BB * HH;
    size_t ofs = (size_t)b * HH;

    for (int t = 0; t < TT; ++t) {
        // deferred, coalesced store of h_{t-1} (drains under FMA phase)
        if (t && tid < HH) io[ofs - stride + tid] = h[tid];
        // xi_t prefetch (consumed in reduce phase; 4x dup per col, coalesced)
        float xr = io[ofs + rcol];

        // wave-uniform broadcast read of this wave's h k-slice
        f4 hv[4];
#pragma unroll
        for (int m = 0; m < 4; ++m)
            hv[m] = *(const f4*)&h[kb + m * 4];

        float acc[4];
#pragma unroll
        for (int c = 0; c < 4; ++c) {
            float s = 0.f;
#pragma unroll
            for (int m = 0; m < 4; ++m) {
                s += w[c][m].x * hv[m].x;
                s += w[c][m].y * hv[m].y;
                s += w[c][m].z * hv[m].z;
                s += w[c][m].w * hv[m].w;
            }
            acc[c] = s;
        }
        *(f4*)&part[q][jb] = (f4){acc[0], acc[1], acc[2], acc[3]};
        __syncthreads();

        // 16 partials per col: 4 LDS reads + 2 in-wave shuffles
        float s = part[rr * 4 + 0][rcol] + part[rr * 4 + 1][rcol]
                + part[rr * 4 + 2][rcol] + part[rr * 4 + 3][rcol];
        s += __shfl_xor(s, 1);
        s += __shfl_xor(s, 2);
        if (rr == 0) h[rcol] = fast_tanh(xr + s);
        __syncthreads();
        ofs += stride;
    }
    if (tid < HH) io[ofs - stride + tid] = h[tid];   // final h store
}

extern "C" void kernel_launch(void* const* d_in, const int* in_sizes, int n_in,
                              void* d_out, int out_size, void* d_ws, size_t ws_size,
                              hipStream_t stream) {
    const float* x  = (const float*)d_in[0];  // [T,B,I]
    const float* h0 = (const float*)d_in[1];  // [B,H]
    const float* Wi = (const float*)d_in[2];  // [H,I]
    const float* Wh = (const float*)d_in[3];  // [H,H]
    const float* bh = (const float*)d_in[4];  // [H]
    float* out = (float*)d_out;               // [T,B,H]

    dim3 pgrid(TT * BB / 64, HH / 64);
    proj_kernel<<<pgrid, 256, 0, stream>>>(x, Wi, bh, out);
    rec_kernel<<<BB, 1024, 0, stream>>>(Wh, h0, out);
}